// Round 1
// baseline (648.365 us; speedup 1.0000x reference)
//
#include <hip/hip_runtime.h>
#include <hip/hip_bf16.h>
#include <cstdint>
#include <cstddef>

#define K_DIM 4096
#define N_DIM 4096
#define BM 128
#define BN 128
#define BK 32

typedef __attribute__((ext_vector_type(8))) short short8;
typedef __attribute__((ext_vector_type(4))) float floatx4;

__device__ __forceinline__ unsigned short f32_bf16_rne(float f) {
    union { float f; unsigned u; } v; v.f = f;
    unsigned r = (v.u + 0x7FFFu + ((v.u >> 16) & 1u)) >> 16;
    return (unsigned short)r;
}

// fp32 -> bf16 cast, 8 elements/thread, 16B stores. Memory-bound.
__global__ __launch_bounds__(256) void cast_f32_bf16_kernel(
        const float* __restrict__ in, unsigned short* __restrict__ out, long n) {
    long i = ((long)blockIdx.x * 256 + threadIdx.x) * 8;
    const long stride = (long)gridDim.x * 256 * 8;
    for (; i < n; i += stride) {
        floatx4 a = *(const floatx4*)(in + i);
        floatx4 b = *(const floatx4*)(in + i + 4);
        union { unsigned short u[8]; short8 v; } r;
#pragma unroll
        for (int j = 0; j < 4; j++) r.u[j] = f32_bf16_rne(a[j]);
#pragma unroll
        for (int j = 0; j < 4; j++) r.u[4 + j] = f32_bf16_rne(b[j]);
        *(short8*)(out + i) = r.v;
    }
}

// m97-structure bf16 GEMM, C = A * B^T.
// A: M x K bf16 row-major. B: N x K bf16 row-major (weights layout). C: M x N fp32.
// 128x128 tile / block of 256 threads (4 waves, 2x2), each wave 4x4 grid of
// 16x16x32 MFMA tiles. Staging via global_load_lds width=16 (wave-uniform
// base + lane*16 => LDS tiles are unpadded row-major [128][32]).
__global__ __launch_bounds__(256) void gemm_bf16_bt(
        const unsigned short* __restrict__ A,
        const unsigned short* __restrict__ B,
        float* __restrict__ C, int M) {
    __shared__ unsigned short sA[BM * BK];   // 8 KiB
    __shared__ unsigned short sB[BN * BK];   // 8 KiB

    const int tid  = threadIdx.x;
    const int lane = tid & 63;
    const int wave = tid >> 6;   // 0..3
    const int wm   = wave >> 1;  // 0..1
    const int wn   = wave & 1;   // 0..1
    const int quad = lane >> 4;  // 0..3
    const int l16  = lane & 15;

    const int bm = blockIdx.y;
    const int bn = blockIdx.x;

    // staging map: thread t covers row t>>2 (and +64 on 2nd issue), cols (t&3)*8..+7
    const int srow = tid >> 2;
    const int scol = (tid & 3) * 8;

    const unsigned short* ag = A + ((size_t)bm * BM + srow) * K_DIM + scol;
    const unsigned short* bg = B + ((size_t)bn * BN + srow) * K_DIM + scol;

    floatx4 acc[4][4];
#pragma unroll
    for (int i = 0; i < 4; i++)
#pragma unroll
        for (int j = 0; j < 4; j++)
            acc[i][j] = (floatx4)0.0f;

    for (int k0 = 0; k0 < K_DIM; k0 += BK) {
        // ---- global -> LDS staging (4 x 4KiB issues) ----
        __builtin_amdgcn_global_load_lds(
            (const __attribute__((address_space(1))) void*)(ag),
            (__attribute__((address_space(3))) void*)(sA + wave * 16 * BK), 16, 0, 0);
        __builtin_amdgcn_global_load_lds(
            (const __attribute__((address_space(1))) void*)(ag + (size_t)64 * K_DIM),
            (__attribute__((address_space(3))) void*)(sA + (64 + wave * 16) * BK), 16, 0, 0);
        __builtin_amdgcn_global_load_lds(
            (const __attribute__((address_space(1))) void*)(bg),
            (__attribute__((address_space(3))) void*)(sB + wave * 16 * BK), 16, 0, 0);
        __builtin_amdgcn_global_load_lds(
            (const __attribute__((address_space(1))) void*)(bg + (size_t)64 * K_DIM),
            (__attribute__((address_space(3))) void*)(sB + (64 + wave * 16) * BK), 16, 0, 0);
        ag += BK;
        bg += BK;
        __syncthreads();   // drains vmcnt (global_load_lds) + barrier

        // ---- LDS -> fragments (ds_read_b128) ----
        // A-operand layout: A[m = lane&15][k = quad*8 + j]
        short8 af[4], bf[4];
#pragma unroll
        for (int mt = 0; mt < 4; mt++)
            af[mt] = *(const short8*)(sA + (wm * 64 + mt * 16 + l16) * BK + quad * 8);
#pragma unroll
        for (int nt = 0; nt < 4; nt++)
            bf[nt] = *(const short8*)(sB + (wn * 64 + nt * 16 + l16) * BK + quad * 8);

        // ---- 16 MFMA / wave / K-iter ----
#pragma unroll
        for (int mt = 0; mt < 4; mt++)
#pragma unroll
            for (int nt = 0; nt < 4; nt++)
                acc[mt][nt] = __builtin_amdgcn_mfma_f32_16x16x32_bf16(
                    af[mt], bf[nt], acc[mt][nt], 0, 0, 0);
        __syncthreads();
    }

    // ---- epilogue: C/D layout col = lane&15, row = quad*4 + reg (m89-verified) ----
#pragma unroll
    for (int mt = 0; mt < 4; mt++) {
#pragma unroll
        for (int nt = 0; nt < 4; nt++) {
            const int col = bn * BN + wn * 64 + nt * 16 + l16;
            const size_t row0 = (size_t)bm * BM + wm * 64 + mt * 16 + quad * 4;
#pragma unroll
            for (int r = 0; r < 4; r++)
                C[(row0 + r) * N_DIM + col] = acc[mt][nt][r];
        }
    }
}

// Correctness fallback if ws_size is too small for the bf16 copies (fp32 vector).
__global__ __launch_bounds__(256) void gemm_naive_f32(
        const float* __restrict__ X, const float* __restrict__ W,
        float* __restrict__ C, long total) {
    long idx = (long)blockIdx.x * 256 + threadIdx.x;
    if (idx >= total) return;
    const long row = idx / N_DIM, col = idx % N_DIM;
    const float* x = X + row * K_DIM;
    const float* w = W + col * K_DIM;
    float s = 0.f;
    for (int k = 0; k < K_DIM; k += 4) {
        floatx4 a = *(const floatx4*)(x + k);
        floatx4 b = *(const floatx4*)(w + k);
        s += a[0] * b[0] + a[1] * b[1] + a[2] * b[2] + a[3] * b[3];
    }
    C[idx] = s;
}

extern "C" void kernel_launch(void* const* d_in, const int* in_sizes, int n_in,
                              void* d_out, int out_size, void* d_ws, size_t ws_size,
                              hipStream_t stream) {
    const float* x = (const float*)d_in[0];   // (4,2048,4096) fp32
    const float* w = (const float*)d_in[1];   // (4096,4096) fp32, (N,K) = B^T layout
    float* out = (float*)d_out;               // (M, 4096) fp32

    const long nx = (long)in_sizes[0];        // M*K
    const long nw = (long)in_sizes[1];        // N*K
    const int  M  = (int)(nx / K_DIM);        // 8192

    const size_t a_bytes = (size_t)nx * 2;    // 64 MiB
    const size_t b_bytes = (size_t)nw * 2;    // 32 MiB

    if (ws_size >= a_bytes + b_bytes) {
        unsigned short* a16 = (unsigned short*)d_ws;
        unsigned short* b16 = (unsigned short*)((char*)d_ws + a_bytes);
        cast_f32_bf16_kernel<<<8192, 256, 0, stream>>>(x, a16, nx);
        cast_f32_bf16_kernel<<<8192, 256, 0, stream>>>(w, b16, nw);
        dim3 grid(N_DIM / BN, M / BM);        // (32, 64)
        gemm_bf16_bt<<<grid, 256, 0, stream>>>(a16, b16, out, M);
    } else {
        const long total = (long)M * N_DIM;
        gemm_naive_f32<<<(int)((total + 255) / 256), 256, 0, stream>>>(x, w, out, total);
    }
}

// Round 2
// 531.962 us; speedup vs baseline: 1.2188x; 1.2188x over previous
//
#include <hip/hip_runtime.h>
#include <hip/hip_bf16.h>
#include <cstdint>
#include <cstddef>

#define K_DIM 4096
#define N_DIM 4096
#define BM 128
#define BN 128
#define BK 64   // halves per LDS row = 128 B = one full bank period

typedef __attribute__((ext_vector_type(8))) short short8;
typedef __attribute__((ext_vector_type(4))) float floatx4;

__device__ __forceinline__ unsigned short f32_bf16_rne(float f) {
    union { float f; unsigned u; } v; v.f = f;
    unsigned r = (v.u + 0x7FFFu + ((v.u >> 16) & 1u)) >> 16;
    return (unsigned short)r;
}

// Fused fp32 -> bf16 cast for both x and w in one launch. 8 elems/thread-chunk.
__global__ __launch_bounds__(256) void cast2_f32_bf16_kernel(
        const float* __restrict__ x, const float* __restrict__ w,
        unsigned short* __restrict__ a16, unsigned short* __restrict__ b16,
        long nx, long nw) {
    const long nchunks = (nx + nw) / 8;
    long c = (long)blockIdx.x * 256 + threadIdx.x;
    const long stride = (long)gridDim.x * 256;
    const long xc = nx / 8;
    for (; c < nchunks; c += stride) {
        const float* src;
        unsigned short* dst;
        long i;
        if (c < xc) { i = c * 8;        src = x + i; dst = a16 + i; }
        else        { i = (c - xc) * 8; src = w + i; dst = b16 + i; }
        floatx4 a = *(const floatx4*)(src);
        floatx4 b = *(const floatx4*)(src + 4);
        union { unsigned short u[8]; short8 v; } r;
#pragma unroll
        for (int j = 0; j < 4; j++) r.u[j] = f32_bf16_rne(a[j]);
#pragma unroll
        for (int j = 0; j < 4; j++) r.u[4 + j] = f32_bf16_rne(b[j]);
        *(short8*)(dst) = r.v;
    }
}

// bf16 GEMM, C = A * B^T. A: MxK bf16 row-major, B: NxK bf16 row-major, C: MxN fp32.
// 128x128 tile / 256 threads (4 waves 2x2), 4x4 16x16x32-MFMA tiles per wave.
// BK=64: LDS row = 128 B (full bank period). 16B blocks XOR-swizzled by row&7:
//   physical_blk = logical_kblk ^ (row & 7)
// => quad's 16 lanes (rows l16, fixed kblk) hit 8 distinct banks = 2-way = free.
// global_load_lds width=16 stages pre-swizzled: lane's source kblk is permuted
// per-lane ((lane&7)^((lane>>3)&7)); LDS dest stays wave-uniform-base + lane*16.
__global__ __launch_bounds__(256) void gemm_bf16_bt(
        const unsigned short* __restrict__ A,
        const unsigned short* __restrict__ B,
        float* __restrict__ C, int M) {
    __shared__ unsigned short sA[BM * BK];   // 16 KiB
    __shared__ unsigned short sB[BN * BK];   // 16 KiB

    const int tid  = threadIdx.x;
    const int lane = tid & 63;
    const int wave = tid >> 6;   // 0..3
    const int wm   = wave >> 1;  // 0..1
    const int wn   = wave & 1;   // 0..1
    const int quad = lane >> 4;  // 0..3
    const int l16  = lane & 15;

    const int bm = blockIdx.y;
    const int bn = blockIdx.x;

    // ---- staging map ----
    // issue i (0..3), wave w: rows i*32 + w*8 + (lane>>3), 8 rows x 128 B = 1 KiB/issue.
    // lane writes LDS at base + lane*16 -> physical blk (lane&7) of row (lane>>3).
    // source logical kblk = (lane&7) ^ (row&7) = (lane&7) ^ ((lane>>3)&7).
    const int srow     = wave * 8 + (lane >> 3);              // row within 32-row slab
    const int kblk_src = (lane & 7) ^ ((lane >> 3) & 7);      // pre-swizzle source blk

    const unsigned short* ag = A + ((size_t)bm * BM + srow) * K_DIM + kblk_src * 8;
    const unsigned short* bg = B + ((size_t)bn * BN + srow) * K_DIM + kblk_src * 8;

    floatx4 acc[4][4];
#pragma unroll
    for (int i = 0; i < 4; i++)
#pragma unroll
        for (int j = 0; j < 4; j++)
            acc[i][j] = (floatx4)0.0f;

    for (int k0 = 0; k0 < K_DIM; k0 += BK) {
        // ---- global -> LDS staging: 4 slabs x (A,B) ----
#pragma unroll
        for (int i = 0; i < 4; i++) {
            __builtin_amdgcn_global_load_lds(
                (const __attribute__((address_space(1))) void*)(ag + (size_t)(i * 32) * K_DIM),
                (__attribute__((address_space(3))) void*)(sA + (i * 32 + wave * 8) * BK),
                16, 0, 0);
            __builtin_amdgcn_global_load_lds(
                (const __attribute__((address_space(1))) void*)(bg + (size_t)(i * 32) * K_DIM),
                (__attribute__((address_space(3))) void*)(sB + (i * 32 + wave * 8) * BK),
                16, 0, 0);
        }
        ag += BK;
        bg += BK;
        __syncthreads();   // drains vmcnt (global_load_lds) + barrier

        // ---- 2 K-steps of 32: LDS -> frags (swizzled, conflict-free) + 16 MFMA ----
#pragma unroll
        for (int s = 0; s < 2; s++) {
            // A-operand layout: A[m = lane&15][k = quad*8 + j]; logical kblk = s*4+quad
            const int pblk = ((s * 4 + quad) ^ (l16 & 7)) * 8;  // physical, in halves
            short8 af[4], bf[4];
#pragma unroll
            for (int mt = 0; mt < 4; mt++)
                af[mt] = *(const short8*)(sA + (wm * 64 + mt * 16 + l16) * BK + pblk);
#pragma unroll
            for (int nt = 0; nt < 4; nt++)
                bf[nt] = *(const short8*)(sB + (wn * 64 + nt * 16 + l16) * BK + pblk);
#pragma unroll
            for (int mt = 0; mt < 4; mt++)
#pragma unroll
                for (int nt = 0; nt < 4; nt++)
                    acc[mt][nt] = __builtin_amdgcn_mfma_f32_16x16x32_bf16(
                        af[mt], bf[nt], acc[mt][nt], 0, 0, 0);
        }
        __syncthreads();
    }

    // ---- epilogue: C/D layout col = lane&15, row = quad*4 + reg (m89-verified) ----
#pragma unroll
    for (int mt = 0; mt < 4; mt++) {
#pragma unroll
        for (int nt = 0; nt < 4; nt++) {
            const int col = bn * BN + wn * 64 + nt * 16 + l16;
            const size_t row0 = (size_t)bm * BM + wm * 64 + mt * 16 + quad * 4;
#pragma unroll
            for (int r = 0; r < 4; r++)
                C[(row0 + r) * N_DIM + col] = acc[mt][nt][r];
        }
    }
}

// Correctness fallback if ws_size too small for bf16 copies (fp32 vector ALU).
__global__ __launch_bounds__(256) void gemm_naive_f32(
        const float* __restrict__ X, const float* __restrict__ W,
        float* __restrict__ C, long total) {
    long idx = (long)blockIdx.x * 256 + threadIdx.x;
    if (idx >= total) return;
    const long row = idx / N_DIM, col = idx % N_DIM;
    const float* x = X + row * K_DIM;
    const float* w = W + col * K_DIM;
    float s = 0.f;
    for (int k = 0; k < K_DIM; k += 4) {
        floatx4 a = *(const floatx4*)(x + k);
        floatx4 b = *(const floatx4*)(w + k);
        s += a[0] * b[0] + a[1] * b[1] + a[2] * b[2] + a[3] * b[3];
    }
    C[idx] = s;
}

extern "C" void kernel_launch(void* const* d_in, const int* in_sizes, int n_in,
                              void* d_out, int out_size, void* d_ws, size_t ws_size,
                              hipStream_t stream) {
    const float* x = (const float*)d_in[0];   // (4,2048,4096) fp32
    const float* w = (const float*)d_in[1];   // (4096,4096) fp32, (N,K) = B^T layout
    float* out = (float*)d_out;               // (M, 4096) fp32

    const long nx = (long)in_sizes[0];        // M*K
    const long nw = (long)in_sizes[1];        // N*K
    const int  M  = (int)(nx / K_DIM);        // 8192

    const size_t a_bytes = (size_t)nx * 2;    // 64 MiB
    const size_t b_bytes = (size_t)nw * 2;    // 32 MiB

    if (ws_size >= a_bytes + b_bytes) {
        unsigned short* a16 = (unsigned short*)d_ws;
        unsigned short* b16 = (unsigned short*)((char*)d_ws + a_bytes);
        cast2_f32_bf16_kernel<<<4096, 256, 0, stream>>>(x, w, a16, b16, nx, nw);
        dim3 grid(N_DIM / BN, M / BM);        // (32, 64)
        gemm_bf16_bt<<<grid, 256, 0, stream>>>(a16, b16, out, M);
    } else {
        const long total = (long)M * N_DIM;
        gemm_naive_f32<<<(int)((total + 255) / 256), 256, 0, stream>>>(x, w, out, total);
    }
}